// Round 5
// baseline (1424.663 us; speedup 1.0000x reference)
//
#include <hip/hip_runtime.h>

typedef float f4 __attribute__((ext_vector_type(4)));

#define NEG 0.2f
constexpr int B_ = 8, N_ = 1024;

// ---------------------------------------------------------------------------
// Kernel 1: h = x @ W^T (M=8192,N=128,K=128) + src/dst projections. Unchanged.
// ---------------------------------------------------------------------------
__global__ __launch_bounds__(256) void gat_h_kernel(
    const float* __restrict__ x, const float* __restrict__ Ww,
    const float* __restrict__ attn,
    float* __restrict__ hfeat, float* __restrict__ srcv, float* __restrict__ dstv)
{
    __shared__ float Wl[128 * 128];
    const int tid = threadIdx.x;
    const int row0 = blockIdx.x * 16;

    #pragma unroll
    for (int k = 0; k < 16; ++k) {
        int f = tid + k * 256;
        int o = f >> 5, ib = f & 31;
        float4 w = *(const float4*)(Ww + o * 128 + ib * 4);
        *(float4*)&Wl[o * 128 + ((ib ^ ((o >> 2) & 7)) << 2)] = w;
    }
    __syncthreads();

    const int colg = tid & 31;
    const int rg   = tid >> 5;
    const int swz  = colg & 7;
    float acc[2][4] = {};
    const float* xr = x + (size_t)(row0 + rg * 2) * 128;

    #pragma unroll 8
    for (int is = 0; is < 32; ++is) {
        float4 x0 = *(const float4*)(xr + is * 4);
        float4 x1 = *(const float4*)(xr + 128 + is * 4);
        #pragma unroll
        for (int cc = 0; cc < 4; ++cc) {
            float4 wv = *(const float4*)&Wl[(colg * 4 + cc) * 128 + ((is ^ swz) << 2)];
            acc[0][cc] = fmaf(x0.x, wv.x, acc[0][cc]);
            acc[0][cc] = fmaf(x0.y, wv.y, acc[0][cc]);
            acc[0][cc] = fmaf(x0.z, wv.z, acc[0][cc]);
            acc[0][cc] = fmaf(x0.w, wv.w, acc[0][cc]);
            acc[1][cc] = fmaf(x1.x, wv.x, acc[1][cc]);
            acc[1][cc] = fmaf(x1.y, wv.y, acc[1][cc]);
            acc[1][cc] = fmaf(x1.z, wv.z, acc[1][cc]);
            acc[1][cc] = fmaf(x1.w, wv.w, acc[1][cc]);
        }
    }
    #pragma unroll
    for (int r = 0; r < 2; ++r) {
        float4 hv = make_float4(acc[r][0], acc[r][1], acc[r][2], acc[r][3]);
        *(float4*)(hfeat + (size_t)(row0 + rg * 2 + r) * 128 + colg * 4) = hv;
    }
    const int hh = colg >> 3;
    float ps[2] = {0.f, 0.f}, pd[2] = {0.f, 0.f};
    #pragma unroll
    for (int cc = 0; cc < 4; ++cc) {
        int fi = (colg & 7) * 4 + cc;
        float as = attn[hh * 65 + fi];
        float ad = attn[hh * 65 + 32 + fi];
        ps[0] = fmaf(acc[0][cc], as, ps[0]); ps[1] = fmaf(acc[1][cc], as, ps[1]);
        pd[0] = fmaf(acc[0][cc], ad, pd[0]); pd[1] = fmaf(acc[1][cc], ad, pd[1]);
    }
    #pragma unroll
    for (int m = 1; m <= 4; m <<= 1) {
        ps[0] += __shfl_xor(ps[0], m); ps[1] += __shfl_xor(ps[1], m);
        pd[0] += __shfl_xor(pd[0], m); pd[1] += __shfl_xor(pd[1], m);
    }
    if ((tid & 7) == 0) {
        #pragma unroll
        for (int r = 0; r < 2; ++r) {
            srcv[(size_t)(row0 + rg * 2 + r) * 4 + hh] = ps[r];
            dstv[(size_t)(row0 + rg * 2 + r) * 4 + hh] = pd[r];
        }
    }
}

// ---------------------------------------------------------------------------
// Kernel 2: 1024 blocks x 512 thr (8 waves), TI=8 rows, b=bid&7 (XCD-local h).
// WAVE-AUTONOMOUS: wave w owns j-slice [w*128, w*128+128). Only 2 block
// barriers total. Per 32-j chunk (lane=(jj32, rh2)):
//   alpha for 4 rows x 4 heads/lane -> nt global store + wave-private LDS slab
//   [h][r*33][jj] (write 2-way free, read 8-addr broadcast free)
//   -> s_waitcnt lgkmcnt(0) (same-wave fence, NO s_barrier)
//   -> PV: lane=(jp2,hh4,fl8): acc[8 rows] f4 over its jp j-subset.
// Epilogue: shfl jp-merge, slab-stage wave partials, 1 barrier, 512-thr sum.
// ---------------------------------------------------------------------------
__global__ __launch_bounds__(512, 4) void gat_attn_kernel(
    const float* __restrict__ adj, const float* __restrict__ attn,
    const float* __restrict__ hfeat, const float* __restrict__ srcv,
    const float* __restrict__ dstv,
    float* __restrict__ out, float* __restrict__ alpha)
{
    __shared__ float slab[8][1056];      // per-wave: [h][r*33][jj] / out-partials
    __shared__ float spart[8][2][16];    // [wave][rh][ri*4+h]

    const int tid  = threadIdx.x;
    const int lane = tid & 63;
    const int w    = tid >> 6;
    const int b    = blockIdx.x & 7;
    const int i0   = (blockIdx.x >> 3) * 8;
    const int jj   = lane & 31;          // j within chunk
    const int rh   = lane >> 5;          // row half: rows rh*4..rh*4+3
    const int jbase = w * 128;           // wave's j-slice

    float aE[4];
    #pragma unroll
    for (int h = 0; h < 4; ++h) aE[h] = attn[h * 65 + 64];

    float src_r[4][4];
    #pragma unroll
    for (int ri = 0; ri < 4; ++ri)
        #pragma unroll
        for (int h = 0; h < 4; ++h)
            src_r[ri][h] = srcv[(size_t)(b * N_ + i0 + rh * 4 + ri) * 4 + h];

    const float* dstb = dstv + (size_t)b * N_ * 4;
    const float* adjr = adj + ((size_t)(b * N_ + i0 + rh * 4)) * N_;

    // ---------------- Pass A: softmax-denominator partials ----------------
    float sp[4][4] = {};
    for (int c = 0; c < 4; ++c) {
        const int j = jbase + c * 32 + jj;
        f4 dv = *(const f4*)(dstb + (size_t)j * 4);
        #pragma unroll
        for (int ri = 0; ri < 4; ++ri) {
            float av = __builtin_nontemporal_load(adjr + (size_t)ri * N_ + j);
            #pragma unroll
            for (int h = 0; h < 4; ++h) {
                float e = fmaf(av, aE[h], src_r[ri][h] + dv[h]);
                e = e >= 0.f ? e : NEG * e;
                sp[ri][h] += (av != 0.f) ? __expf(e) : 0.f;
            }
        }
    }
    #pragma unroll
    for (int m = 1; m <= 16; m <<= 1) {
        #pragma unroll
        for (int ri = 0; ri < 4; ++ri)
            #pragma unroll
            for (int h = 0; h < 4; ++h)
                sp[ri][h] += __shfl_xor(sp[ri][h], m);
    }
    if (jj == 0) {
        #pragma unroll
        for (int ri = 0; ri < 4; ++ri)
            #pragma unroll
            for (int h = 0; h < 4; ++h)
                spart[w][rh][ri * 4 + h] = sp[ri][h];
    }
    __syncthreads();                                   // barrier #1
    float rs_r[4][4];
    #pragma unroll
    for (int ri = 0; ri < 4; ++ri)
        #pragma unroll
        for (int h = 0; h < 4; ++h) {
            float s = 0.f;
            #pragma unroll
            for (int ww = 0; ww < 8; ++ww) s += spart[ww][rh][ri * 4 + h];
            rs_r[ri][h] = s > 0.f ? 1.f / s : 0.f;
        }

    // ---------------- Main loop: 4 chunks of 32 j, barrier-free ----------
    const int jp  = lane >> 5;           // PV mapping
    const int hhp = (lane >> 3) & 3;
    const int fl  = lane & 7;
    const int col = hhp * 32 + fl * 4;
    float* slabw = &slab[w][0];

    f4 acc[8];
    #pragma unroll
    for (int r = 0; r < 8; ++r) acc[r] = (f4)0.f;

    // prologue loads for chunk 0
    float av_c[4];
    f4 dv_c;
    {
        const int j = jbase + jj;
        dv_c = *(const f4*)(dstb + (size_t)j * 4);
        #pragma unroll
        for (int ri = 0; ri < 4; ++ri)
            av_c[ri] = __builtin_nontemporal_load(adjr + (size_t)ri * N_ + j);
    }

    for (int c = 0; c < 4; ++c) {
        const int j0 = jbase + c * 32;
        const int j  = j0 + jj;
        // fence: previous chunk's slab reads complete before overwrite
        asm volatile("s_waitcnt lgkmcnt(0)" ::: "memory");
        // alpha compute from prefetched av_c/dv_c -> slab + nt global
        #pragma unroll
        for (int ri = 0; ri < 4; ++ri) {
            f4 al;
            #pragma unroll
            for (int h = 0; h < 4; ++h) {
                float e = fmaf(av_c[ri], aE[h], src_r[ri][h] + dv_c[h]);
                e = e >= 0.f ? e : NEG * e;
                al[h] = (av_c[ri] != 0.f) ? __expf(e) * rs_r[ri][h] : 0.f;
            }
            #pragma unroll
            for (int h = 0; h < 4; ++h)
                slabw[h * 264 + (rh * 4 + ri) * 33 + jj] = al[h];
            __builtin_nontemporal_store(
                al, (f4*)(alpha + ((size_t)(b * N_ + i0 + rh * 4 + ri) * N_ + j) * 4));
        }
        // prefetch next chunk's inputs (overlaps PV below)
        if (c < 3) {
            const int jn = j + 32;
            dv_c = *(const f4*)(dstb + (size_t)jn * 4);
            #pragma unroll
            for (int ri = 0; ri < 4; ++ri)
                av_c[ri] = __builtin_nontemporal_load(adjr + (size_t)ri * N_ + jn);
        }
        // fence: slab writes visible to all lanes of this wave
        asm volatile("s_waitcnt lgkmcnt(0)" ::: "memory");
        // PV over this chunk's 32 j (jp splits even/odd)
        #pragma unroll
        for (int s = 0; s < 16; ++s) {
            const int jl = s * 2 + jp;
            f4 hv = *(const f4*)(hfeat + (size_t)(b * N_ + j0 + jl) * 128 + col);
            float a0 = slabw[hhp * 264 + 0 * 33 + jl];
            float a1 = slabw[hhp * 264 + 1 * 33 + jl];
            float a2 = slabw[hhp * 264 + 2 * 33 + jl];
            float a3 = slabw[hhp * 264 + 3 * 33 + jl];
            float a4 = slabw[hhp * 264 + 4 * 33 + jl];
            float a5 = slabw[hhp * 264 + 5 * 33 + jl];
            float a6 = slabw[hhp * 264 + 6 * 33 + jl];
            float a7 = slabw[hhp * 264 + 7 * 33 + jl];
            acc[0] += a0 * hv; acc[1] += a1 * hv;
            acc[2] += a2 * hv; acc[3] += a3 * hv;
            acc[4] += a4 * hv; acc[5] += a5 * hv;
            acc[6] += a6 * hv; acc[7] += a7 * hv;
        }
    }

    // ---------------- Epilogue: merge jp halves, cross-wave reduce --------
    #pragma unroll
    for (int r = 0; r < 8; ++r) {
        acc[r].x += __shfl_xor(acc[r].x, 32);
        acc[r].y += __shfl_xor(acc[r].y, 32);
        acc[r].z += __shfl_xor(acc[r].z, 32);
        acc[r].w += __shfl_xor(acc[r].w, 32);
    }
    asm volatile("s_waitcnt lgkmcnt(0)" ::: "memory");  // PV reads done
    if (jp == 0) {
        #pragma unroll
        for (int r = 0; r < 8; ++r)
            *(f4*)&slab[w][r * 132 + col] = acc[r];
    }
    __syncthreads();                                   // barrier #2
    #pragma unroll
    for (int k = 0; k < 2; ++k) {
        const int o = tid + k * 512;
        const int r = o >> 7, cc = o & 127;
        float s = 0.f;
        #pragma unroll
        for (int ww = 0; ww < 8; ++ww) s += slab[ww][r * 132 + cc];
        out[(size_t)(b * N_ + i0 + r) * 128 + cc] = s;
    }
}

extern "C" void kernel_launch(void* const* d_in, const int* in_sizes, int n_in,
                              void* d_out, int out_size, void* d_ws, size_t ws_size,
                              hipStream_t stream) {
    const float* x    = (const float*)d_in[0];
    const float* adj  = (const float*)d_in[1];
    const float* Ww   = (const float*)d_in[2];
    const float* attn = (const float*)d_in[3];

    float* out   = (float*)d_out;                    // [8,1024,128]
    float* alpha = out + (size_t)B_ * N_ * 128;      // [8,1024,1024,4]

    float* hfeat = (float*)d_ws;                     // 4 MB
    float* srcv  = hfeat + (size_t)B_ * N_ * 128;
    float* dstv  = srcv + (size_t)B_ * N_ * 4;

    gat_h_kernel<<<512, 256, 0, stream>>>(x, Ww, attn, hfeat, srcv, dstv);
    gat_attn_kernel<<<1024, 512, 0, stream>>>(adj, attn, hfeat, srcv, dstv, out, alpha);
}

// Round 6
// 1422.500 us; speedup vs baseline: 1.0015x; 1.0015x over previous
//
#include <hip/hip_runtime.h>

typedef float f4 __attribute__((ext_vector_type(4)));

#define NEG 0.2f
constexpr int B_ = 8, N_ = 1024;

// ---------------------------------------------------------------------------
// Kernel 1: h = x @ W^T (M=8192,N=128,K=128) + src/dst projections. Unchanged.
// ---------------------------------------------------------------------------
__global__ __launch_bounds__(256) void gat_h_kernel(
    const float* __restrict__ x, const float* __restrict__ Ww,
    const float* __restrict__ attn,
    float* __restrict__ hfeat, float* __restrict__ srcv, float* __restrict__ dstv)
{
    __shared__ float Wl[128 * 128];
    const int tid = threadIdx.x;
    const int row0 = blockIdx.x * 16;

    #pragma unroll
    for (int k = 0; k < 16; ++k) {
        int f = tid + k * 256;
        int o = f >> 5, ib = f & 31;
        float4 w = *(const float4*)(Ww + o * 128 + ib * 4);
        *(float4*)&Wl[o * 128 + ((ib ^ ((o >> 2) & 7)) << 2)] = w;
    }
    __syncthreads();

    const int colg = tid & 31;
    const int rg   = tid >> 5;
    const int swz  = colg & 7;
    float acc[2][4] = {};
    const float* xr = x + (size_t)(row0 + rg * 2) * 128;

    #pragma unroll 8
    for (int is = 0; is < 32; ++is) {
        float4 x0 = *(const float4*)(xr + is * 4);
        float4 x1 = *(const float4*)(xr + 128 + is * 4);
        #pragma unroll
        for (int cc = 0; cc < 4; ++cc) {
            float4 wv = *(const float4*)&Wl[(colg * 4 + cc) * 128 + ((is ^ swz) << 2)];
            acc[0][cc] = fmaf(x0.x, wv.x, acc[0][cc]);
            acc[0][cc] = fmaf(x0.y, wv.y, acc[0][cc]);
            acc[0][cc] = fmaf(x0.z, wv.z, acc[0][cc]);
            acc[0][cc] = fmaf(x0.w, wv.w, acc[0][cc]);
            acc[1][cc] = fmaf(x1.x, wv.x, acc[1][cc]);
            acc[1][cc] = fmaf(x1.y, wv.y, acc[1][cc]);
            acc[1][cc] = fmaf(x1.z, wv.z, acc[1][cc]);
            acc[1][cc] = fmaf(x1.w, wv.w, acc[1][cc]);
        }
    }
    #pragma unroll
    for (int r = 0; r < 2; ++r) {
        float4 hv = make_float4(acc[r][0], acc[r][1], acc[r][2], acc[r][3]);
        *(float4*)(hfeat + (size_t)(row0 + rg * 2 + r) * 128 + colg * 4) = hv;
    }
    const int hh = colg >> 3;
    float ps[2] = {0.f, 0.f}, pd[2] = {0.f, 0.f};
    #pragma unroll
    for (int cc = 0; cc < 4; ++cc) {
        int fi = (colg & 7) * 4 + cc;
        float as = attn[hh * 65 + fi];
        float ad = attn[hh * 65 + 32 + fi];
        ps[0] = fmaf(acc[0][cc], as, ps[0]); ps[1] = fmaf(acc[1][cc], as, ps[1]);
        pd[0] = fmaf(acc[0][cc], ad, pd[0]); pd[1] = fmaf(acc[1][cc], ad, pd[1]);
    }
    #pragma unroll
    for (int m = 1; m <= 4; m <<= 1) {
        ps[0] += __shfl_xor(ps[0], m); ps[1] += __shfl_xor(ps[1], m);
        pd[0] += __shfl_xor(pd[0], m); pd[1] += __shfl_xor(pd[1], m);
    }
    if ((tid & 7) == 0) {
        #pragma unroll
        for (int r = 0; r < 2; ++r) {
            srcv[(size_t)(row0 + rg * 2 + r) * 4 + hh] = ps[r];
            dstv[(size_t)(row0 + rg * 2 + r) * 4 + hh] = pd[r];
        }
    }
}

// ---------------------------------------------------------------------------
// Kernel 2: 1024 blocks x 512 thr (8 waves), TI=8 rows, b=bid&7 (XCD-local h).
// Wave-autonomous (2 block barriers total). Per 32-j chunk:
//   alpha (4 rows x 4 heads/lane) -> PLAIN f4 global store (through L2;
//   each wave instr covers 2x512B full lines -> no RFO) + wave-private LDS
//   slab [h][r*33][jj]; lgkmcnt-only intra-wave fences; prefetched adj/dst.
//   PV: lane=(jp2,hh4,fl8): acc[8 rows] f4; conflict-free broadcast slab reads.
// NOTE: NO nontemporal stores — nt 16B stores bypass L2 and trigger ~16x
// HBM RMW amplification (round 5: WRITE 2.25GB, FETCH 1.29GB). nt LOADS ok.
// ---------------------------------------------------------------------------
__global__ __launch_bounds__(512, 4) void gat_attn_kernel(
    const float* __restrict__ adj, const float* __restrict__ attn,
    const float* __restrict__ hfeat, const float* __restrict__ srcv,
    const float* __restrict__ dstv,
    float* __restrict__ out, float* __restrict__ alpha)
{
    __shared__ float slab[8][1056];      // per-wave: [h][r*33][jj] / out-partials
    __shared__ float spart[8][2][16];    // [wave][rh][ri*4+h]

    const int tid  = threadIdx.x;
    const int lane = tid & 63;
    const int w    = tid >> 6;
    const int b    = blockIdx.x & 7;
    const int i0   = (blockIdx.x >> 3) * 8;
    const int jj   = lane & 31;          // j within chunk
    const int rh   = lane >> 5;          // row half: rows rh*4..rh*4+3
    const int jbase = w * 128;           // wave's j-slice

    float aE[4];
    #pragma unroll
    for (int h = 0; h < 4; ++h) aE[h] = attn[h * 65 + 64];

    float src_r[4][4];
    #pragma unroll
    for (int ri = 0; ri < 4; ++ri)
        #pragma unroll
        for (int h = 0; h < 4; ++h)
            src_r[ri][h] = srcv[(size_t)(b * N_ + i0 + rh * 4 + ri) * 4 + h];

    const float* dstb = dstv + (size_t)b * N_ * 4;
    const float* adjr = adj + ((size_t)(b * N_ + i0 + rh * 4)) * N_;

    // ---------------- Pass A: softmax-denominator partials ----------------
    float sp[4][4] = {};
    for (int c = 0; c < 4; ++c) {
        const int j = jbase + c * 32 + jj;
        f4 dv = *(const f4*)(dstb + (size_t)j * 4);
        #pragma unroll
        for (int ri = 0; ri < 4; ++ri) {
            float av = __builtin_nontemporal_load(adjr + (size_t)ri * N_ + j);
            #pragma unroll
            for (int h = 0; h < 4; ++h) {
                float e = fmaf(av, aE[h], src_r[ri][h] + dv[h]);
                e = e >= 0.f ? e : NEG * e;
                sp[ri][h] += (av != 0.f) ? __expf(e) : 0.f;
            }
        }
    }
    #pragma unroll
    for (int m = 1; m <= 16; m <<= 1) {
        #pragma unroll
        for (int ri = 0; ri < 4; ++ri)
            #pragma unroll
            for (int h = 0; h < 4; ++h)
                sp[ri][h] += __shfl_xor(sp[ri][h], m);
    }
    if (jj == 0) {
        #pragma unroll
        for (int ri = 0; ri < 4; ++ri)
            #pragma unroll
            for (int h = 0; h < 4; ++h)
                spart[w][rh][ri * 4 + h] = sp[ri][h];
    }
    __syncthreads();                                   // barrier #1
    float rs_r[4][4];
    #pragma unroll
    for (int ri = 0; ri < 4; ++ri)
        #pragma unroll
        for (int h = 0; h < 4; ++h) {
            float s = 0.f;
            #pragma unroll
            for (int ww = 0; ww < 8; ++ww) s += spart[ww][rh][ri * 4 + h];
            rs_r[ri][h] = s > 0.f ? 1.f / s : 0.f;
        }

    // ---------------- Main loop: 4 chunks of 32 j, barrier-free ----------
    const int jp  = lane >> 5;           // PV mapping
    const int hhp = (lane >> 3) & 3;
    const int fl  = lane & 7;
    const int col = hhp * 32 + fl * 4;
    float* slabw = &slab[w][0];

    f4 acc[8];
    #pragma unroll
    for (int r = 0; r < 8; ++r) acc[r] = (f4)0.f;

    // prologue loads for chunk 0
    float av_c[4];
    f4 dv_c;
    {
        const int j = jbase + jj;
        dv_c = *(const f4*)(dstb + (size_t)j * 4);
        #pragma unroll
        for (int ri = 0; ri < 4; ++ri)
            av_c[ri] = __builtin_nontemporal_load(adjr + (size_t)ri * N_ + j);
    }

    for (int c = 0; c < 4; ++c) {
        const int j0 = jbase + c * 32;
        const int j  = j0 + jj;
        // fence: previous chunk's slab reads complete before overwrite
        asm volatile("s_waitcnt lgkmcnt(0)" ::: "memory");
        // alpha compute from prefetched av_c/dv_c -> slab + PLAIN global store
        #pragma unroll
        for (int ri = 0; ri < 4; ++ri) {
            f4 al;
            #pragma unroll
            for (int h = 0; h < 4; ++h) {
                float e = fmaf(av_c[ri], aE[h], src_r[ri][h] + dv_c[h]);
                e = e >= 0.f ? e : NEG * e;
                al[h] = (av_c[ri] != 0.f) ? __expf(e) * rs_r[ri][h] : 0.f;
            }
            #pragma unroll
            for (int h = 0; h < 4; ++h)
                slabw[h * 264 + (rh * 4 + ri) * 33 + jj] = al[h];
            *(f4*)(alpha + ((size_t)(b * N_ + i0 + rh * 4 + ri) * N_ + j) * 4) = al;
        }
        // prefetch next chunk's inputs (overlaps PV below)
        if (c < 3) {
            const int jn = j + 32;
            dv_c = *(const f4*)(dstb + (size_t)jn * 4);
            #pragma unroll
            for (int ri = 0; ri < 4; ++ri)
                av_c[ri] = __builtin_nontemporal_load(adjr + (size_t)ri * N_ + jn);
        }
        // fence: slab writes visible to all lanes of this wave
        asm volatile("s_waitcnt lgkmcnt(0)" ::: "memory");
        // PV over this chunk's 32 j (jp splits even/odd)
        #pragma unroll
        for (int s = 0; s < 16; ++s) {
            const int jl = s * 2 + jp;
            f4 hv = *(const f4*)(hfeat + (size_t)(b * N_ + j0 + jl) * 128 + col);
            float a0 = slabw[hhp * 264 + 0 * 33 + jl];
            float a1 = slabw[hhp * 264 + 1 * 33 + jl];
            float a2 = slabw[hhp * 264 + 2 * 33 + jl];
            float a3 = slabw[hhp * 264 + 3 * 33 + jl];
            float a4 = slabw[hhp * 264 + 4 * 33 + jl];
            float a5 = slabw[hhp * 264 + 5 * 33 + jl];
            float a6 = slabw[hhp * 264 + 6 * 33 + jl];
            float a7 = slabw[hhp * 264 + 7 * 33 + jl];
            acc[0] += a0 * hv; acc[1] += a1 * hv;
            acc[2] += a2 * hv; acc[3] += a3 * hv;
            acc[4] += a4 * hv; acc[5] += a5 * hv;
            acc[6] += a6 * hv; acc[7] += a7 * hv;
        }
    }

    // ---------------- Epilogue: merge jp halves, cross-wave reduce --------
    #pragma unroll
    for (int r = 0; r < 8; ++r) {
        acc[r].x += __shfl_xor(acc[r].x, 32);
        acc[r].y += __shfl_xor(acc[r].y, 32);
        acc[r].z += __shfl_xor(acc[r].z, 32);
        acc[r].w += __shfl_xor(acc[r].w, 32);
    }
    asm volatile("s_waitcnt lgkmcnt(0)" ::: "memory");  // PV reads done
    if (jp == 0) {
        #pragma unroll
        for (int r = 0; r < 8; ++r)
            *(f4*)&slab[w][r * 132 + col] = acc[r];
    }
    __syncthreads();                                   // barrier #2
    #pragma unroll
    for (int k = 0; k < 2; ++k) {
        const int o = tid + k * 512;
        const int r = o >> 7, cc = o & 127;
        float s = 0.f;
        #pragma unroll
        for (int ww = 0; ww < 8; ++ww) s += slab[ww][r * 132 + cc];
        out[(size_t)(b * N_ + i0 + r) * 128 + cc] = s;
    }
}

extern "C" void kernel_launch(void* const* d_in, const int* in_sizes, int n_in,
                              void* d_out, int out_size, void* d_ws, size_t ws_size,
                              hipStream_t stream) {
    const float* x    = (const float*)d_in[0];
    const float* adj  = (const float*)d_in[1];
    const float* Ww   = (const float*)d_in[2];
    const float* attn = (const float*)d_in[3];

    float* out   = (float*)d_out;                    // [8,1024,128]
    float* alpha = out + (size_t)B_ * N_ * 128;      // [8,1024,1024,4]

    float* hfeat = (float*)d_ws;                     // 4 MB
    float* srcv  = hfeat + (size_t)B_ * N_ * 128;
    float* dstv  = srcv + (size_t)B_ * N_ * 4;

    gat_h_kernel<<<512, 256, 0, stream>>>(x, Ww, attn, hfeat, srcv, dstv);
    gat_attn_kernel<<<1024, 512, 0, stream>>>(adj, attn, hfeat, srcv, dstv, out, alpha);
}